// Round 3
// baseline (759.275 us; speedup 1.0000x reference)
//
#include <hip/hip_runtime.h>
#include <math.h>

// ---------- types & helpers ----------
typedef __bf16 bf16x8 __attribute__((ext_vector_type(8)));
typedef unsigned short u16x8 __attribute__((ext_vector_type(8)));
typedef float f32x4 __attribute__((ext_vector_type(4)));

__device__ __forceinline__ float bf2f(unsigned short u) {
  union { unsigned u; float f; } v; v.u = ((unsigned)u) << 16; return v.f;
}
__device__ __forceinline__ unsigned short f2bf(float f) {
  union { float f; unsigned u; } v; v.f = f;
  unsigned r = v.u + 0x7fffu + ((v.u >> 16) & 1u);
  return (unsigned short)(r >> 16);
}
__device__ __forceinline__ bf16x8 ld8(const unsigned short* p) {
  return __builtin_bit_cast(bf16x8, *(const u16x8*)p);
}
__device__ __forceinline__ bf16x8 ld8f(const float* p) {
  f32x4 a = *(const f32x4*)p;
  f32x4 b = *(const f32x4*)(p + 4);
  u16x8 u;
#pragma unroll
  for (int i = 0; i < 4; ++i) { u[i] = f2bf(a[i]); u[4 + i] = f2bf(b[i]); }
  return __builtin_bit_cast(bf16x8, u);
}
// dtype-adaptive loads/stores (isf: 1 = buffers are f32, 0 = bf16)
__device__ __forceinline__ float ldS(const void* p, int isf, size_t i) {
  return isf ? ((const float*)p)[i] : bf2f(((const unsigned short*)p)[i]);
}
__device__ __forceinline__ bf16x8 ld8G(const void* p, int isf, size_t i) {
  return isf ? ld8f((const float*)p + i) : ld8((const unsigned short*)p + i);
}
__device__ __forceinline__ void stO(void* p, int isf, size_t i, float v) {
  if (isf) ((float*)p)[i] = v; else ((unsigned short*)p)[i] = f2bf(v);
}
__device__ __forceinline__ bf16x8 zero8() {
  u16x8 z;
#pragma unroll
  for (int i = 0; i < 8; ++i) z[i] = 0;
  return __builtin_bit_cast(bf16x8, z);
}
__device__ __forceinline__ f32x4 fzero4() {
  f32x4 z; z[0] = z[1] = z[2] = z[3] = 0.f; return z;
}
__device__ __forceinline__ f32x4 mfma16(bf16x8 a, bf16x8 b, f32x4 c) {
  return __builtin_amdgcn_mfma_f32_16x16x32_bf16(a, b, c, 0, 0, 0);
}
__device__ __forceinline__ float scrub(float v) {
  // NaN/Inf/garbage -> finite; no-op for sane data (fminf/fmaxf drop NaN operand)
  return fminf(fmaxf(v, -1e6f), 1e6f);
}

#define C_DIM 96
#define NTOK 128
#define QKV_STR 296
#define XO_STR 104
#define P_STR 136
#define Z_STR 104
#define H_STR 392

// =====================================================================
// dtype sniffer: reads first 256 u16 (512 B) of x — in bounds either way.
// bf16 data: exponent fields ~[0x6E,0x82] -> ~0 weird.
// f32 data read as u16: low halves are random mantissa bits -> ~56/256 weird.
__global__ void dtype_sniff(const unsigned short* __restrict__ x, int* __restrict__ flag) {
  int lane = threadIdx.x;  // 64 threads
  int weird = 0;
#pragma unroll
  for (int k = 0; k < 4; ++k) {
    unsigned short w = x[lane * 4 + k];
    int e = (w >> 7) & 0xFF;
    if (e >= 0xC0 || (e != 0 && e <= 0x30)) weird++;
  }
#pragma unroll
  for (int d = 1; d < 64; d <<= 1) weird += __shfl_xor(weird, d, 64);
  if (lane == 0) *flag = (weird > 16) ? 1 : 0;
}

// =====================================================================
// Kernel A: LN1 + shift + window attention + proj + residual -> y (in d_out)
// one block (384 thr = 6 waves) per window; 2048 windows
// =====================================================================
__global__ __launch_bounds__(384) void swin_attn_kernel(
    const void* __restrict__ x,
    const void* __restrict__ g1,
    const void* __restrict__ b1,
    const void* __restrict__ w_qkv,
    const void* __restrict__ b_qkv,
    const void* __restrict__ w_proj,
    const void* __restrict__ b_proj,
    void* __restrict__ y,
    const int* __restrict__ flag)
{
  __shared__ unsigned short sm_qkv[NTOK * QKV_STR];
  __shared__ unsigned short sm_xo[NTOK * XO_STR];
  __shared__ unsigned short sm_p[6 * 16 * P_STR];
  __shared__ float sm_red[2][3][NTOK];
  __shared__ int sm_tok[NTOK];
  __shared__ int sm_cls[NTOK];

  const int isf = *flag;
  const int tid = threadIdx.x;
  const int win = blockIdx.x;
  const int b = win >> 10;
  const int rem = win & 1023;
  const int ti = rem >> 8, hi = (rem >> 4) & 15, wi = rem & 15;

  // ---- Stage 1: gather (cyclic shift) + LN1 ----
  {
    const int n = tid & 127;
    const int part = tid >> 7;
    const int td = n >> 6, hh = (n >> 3) & 7, ww = n & 7;
    const int t = ti * 2 + td, h = hi * 8 + hh, w = wi * 8 + ww;
    const int ts = (t + 1) & 7, hs = (h + 4) & 127, ws = (w + 4) & 127;
    const int tok = ((b * 8 + ts) * 128 + hs) * 128 + ws;
    if (part == 0) {
      sm_tok[n] = tok;
      int ct = (t < 6) ? 0 : (t - 5);
      int ch = (h < 120) ? 0 : ((h < 124) ? 1 : 2);
      int cw = (w < 120) ? 0 : ((w < 124) ? 1 : 2);
      sm_cls[n] = ct * 9 + ch * 3 + cw;
    }
    float v[32];
    if (isf) {
      const float* xp = (const float*)x + (size_t)tok * C_DIM + part * 32;
      f32x4 raw[8];
#pragma unroll
      for (int i = 0; i < 8; ++i) raw[i] = ((const f32x4*)xp)[i];
#pragma unroll
      for (int i = 0; i < 32; ++i) v[i] = raw[i >> 2][i & 3];
    } else {
      const unsigned short* xp = (const unsigned short*)x + (size_t)tok * C_DIM + part * 32;
      u16x8 raw[4];
#pragma unroll
      for (int i = 0; i < 4; ++i) raw[i] = ((const u16x8*)xp)[i];
#pragma unroll
      for (int i = 0; i < 32; ++i) v[i] = bf2f(raw[i >> 3][i & 7]);
    }
    float s = 0.f, s2 = 0.f;
#pragma unroll
    for (int i = 0; i < 32; ++i) {
      v[i] = scrub(v[i]);
      s += v[i]; s2 += v[i] * v[i];
    }
    sm_red[0][part][n] = s;
    sm_red[1][part][n] = s2;
    __syncthreads();
    float tsum = sm_red[0][0][n] + sm_red[0][1][n] + sm_red[0][2][n];
    float tsq  = sm_red[1][0][n] + sm_red[1][1][n] + sm_red[1][2][n];
    float mean = tsum * (1.0f / 96.0f);
    float var = fmaxf(tsq * (1.0f / 96.0f) - mean * mean, 0.0f);
    float rstd = rsqrtf(var + 1e-5f);
#pragma unroll
    for (int i = 0; i < 32; ++i) {
      int c = part * 32 + i;
      sm_xo[n * XO_STR + c] = f2bf((v[i] - mean) * rstd * ldS(g1, isf, c) + ldS(b1, isf, c));
    }
  }
  __syncthreads();

  const int wv = tid >> 6;
  const int lane = tid & 63;
  const int quad = lane >> 4;
  const int l16 = lane & 15;

  // ---- Stage 2: QKV GEMM (M=128, N=288, K=96); q scaled by 0.25 ----
  {
#pragma unroll
    for (int nt3 = 0; nt3 < 3; ++nt3) {
      const int jcol = (wv * 3 + nt3) * 16 + l16;
      bf16x8 bq[3];
#pragma unroll
      for (int kt = 0; kt < 3; ++kt)
        bq[kt] = ld8G(w_qkv, isf, (size_t)jcol * C_DIM + kt * 32 + quad * 8);
      const float bias = ldS(b_qkv, isf, jcol);
      const float scl = (jcol < C_DIM) ? 0.25f : 1.0f;
      for (int mt = 0; mt < 8; ++mt) {
        f32x4 acc = fzero4();
#pragma unroll
        for (int kt = 0; kt < 3; ++kt) {
          bf16x8 a = ld8(sm_xo + (mt * 16 + l16) * XO_STR + kt * 32 + quad * 8);
          acc = mfma16(a, bq[kt], acc);
        }
#pragma unroll
        for (int r = 0; r < 4; ++r) {
          int row = mt * 16 + quad * 4 + r;
          sm_qkv[row * QKV_STR + jcol] = f2bf((acc[r] + bias) * scl);
        }
      }
    }
  }
  __syncthreads();

  // ---- Stage 3: attention, one head per wave ----
  {
    const int hd = wv;
    const int qoff = hd * 16, koff = C_DIM + hd * 16, voff = 2 * C_DIM + hd * 16;
    bf16x8 bk[8];
#pragma unroll
    for (int nt = 0; nt < 8; ++nt)
      bk[nt] = (quad < 2) ? ld8(sm_qkv + (nt * 16 + l16) * QKV_STR + koff + quad * 8)
                          : zero8();
    bf16x8 bv[4];
#pragma unroll
    for (int kt = 0; kt < 4; ++kt) {
      u16x8 u;
#pragma unroll
      for (int j = 0; j < 8; ++j)
        u[j] = sm_qkv[(kt * 32 + quad * 8 + j) * QKV_STR + voff + l16];
      bv[kt] = __builtin_bit_cast(bf16x8, u);
    }
    unsigned short* pbase = sm_p + wv * 16 * P_STR;

    for (int mt = 0; mt < 8; ++mt) {
      bf16x8 aq = (quad < 2) ? ld8(sm_qkv + (mt * 16 + l16) * QKV_STR + qoff + quad * 8)
                             : zero8();
      f32x4 s[8];
#pragma unroll
      for (int nt = 0; nt < 8; ++nt) s[nt] = mfma16(aq, bk[nt], fzero4());
      int ccls[8];
#pragma unroll
      for (int nt = 0; nt < 8; ++nt) ccls[nt] = sm_cls[nt * 16 + l16];
#pragma unroll
      for (int r = 0; r < 4; ++r) {
        int rc = sm_cls[mt * 16 + quad * 4 + r];
#pragma unroll
        for (int nt = 0; nt < 8; ++nt)
          if (ccls[nt] != rc) s[nt][r] += -100.0f;
      }
#pragma unroll
      for (int r = 0; r < 4; ++r) {
        float m = s[0][r];
#pragma unroll
        for (int nt = 1; nt < 8; ++nt) m = fmaxf(m, s[nt][r]);
#pragma unroll
        for (int d = 1; d < 16; d <<= 1) m = fmaxf(m, __shfl_xor(m, d, 64));
        float e[8], sum = 0.f;
#pragma unroll
        for (int nt = 0; nt < 8; ++nt) { e[nt] = __expf(s[nt][r] - m); sum += e[nt]; }
#pragma unroll
        for (int d = 1; d < 16; d <<= 1) sum += __shfl_xor(sum, d, 64);
        float inv = 1.0f / sum;
#pragma unroll
        for (int nt = 0; nt < 8; ++nt)
          pbase[(quad * 4 + r) * P_STR + nt * 16 + l16] = f2bf(e[nt] * inv);
      }
      __syncthreads();
      f32x4 o = fzero4();
#pragma unroll
      for (int kt = 0; kt < 4; ++kt) {
        bf16x8 ap = ld8(pbase + l16 * P_STR + kt * 32 + quad * 8);
        o = mfma16(ap, bv[kt], o);
      }
#pragma unroll
      for (int r = 0; r < 4; ++r)
        sm_xo[(mt * 16 + quad * 4 + r) * XO_STR + qoff + l16] = f2bf(o[r]);
    }
  }
  __syncthreads();

  // ---- Stage 4: proj + residual + scatter ----
  {
    const int jcol = wv * 16 + l16;
    bf16x8 bp[3];
#pragma unroll
    for (int kt = 0; kt < 3; ++kt)
      bp[kt] = ld8G(w_proj, isf, (size_t)jcol * C_DIM + kt * 32 + quad * 8);
    const float bias = ldS(b_proj, isf, jcol);
    for (int mt = 0; mt < 8; ++mt) {
      f32x4 acc = fzero4();
#pragma unroll
      for (int kt = 0; kt < 3; ++kt) {
        bf16x8 a = ld8(sm_xo + (mt * 16 + l16) * XO_STR + kt * 32 + quad * 8);
        acc = mfma16(a, bp[kt], acc);
      }
#pragma unroll
      for (int r = 0; r < 4; ++r) {
        int row = mt * 16 + quad * 4 + r;
        size_t addr = (size_t)sm_tok[row] * C_DIM + jcol;
        stO(y, isf, addr, scrub(ldS(x, isf, addr)) + acc[r] + bias);
      }
    }
  }
}

// =====================================================================
// Kernel B: LN2 + fc1 + GELU + fc2 + residual; y lives in d_out, in place
// =====================================================================
__global__ __launch_bounds__(384) void swin_mlp_kernel(
    const void* __restrict__ g2,
    const void* __restrict__ b2,
    const void* __restrict__ w_fc1,
    const void* __restrict__ b_fc1,
    const void* __restrict__ w_fc2,
    const void* __restrict__ b_fc2,
    void* __restrict__ yout,
    const int* __restrict__ flag)
{
  __shared__ unsigned short sm_z[NTOK * Z_STR];
  __shared__ unsigned short sm_h[NTOK * H_STR];
  __shared__ float sm_red[2][3][NTOK];

  const int isf = *flag;
  const int tid = threadIdx.x;
  const size_t tok0 = (size_t)blockIdx.x * NTOK;

  // ---- LN2 ----
  {
    const int n = tid & 127;
    const int part = tid >> 7;
    float v[32];
    if (isf) {
      const float* yp = (const float*)yout + (tok0 + n) * C_DIM + part * 32;
      f32x4 raw[8];
#pragma unroll
      for (int i = 0; i < 8; ++i) raw[i] = ((const f32x4*)yp)[i];
#pragma unroll
      for (int i = 0; i < 32; ++i) v[i] = raw[i >> 2][i & 3];
    } else {
      const unsigned short* yp = (const unsigned short*)yout + (tok0 + n) * C_DIM + part * 32;
      u16x8 raw[4];
#pragma unroll
      for (int i = 0; i < 4; ++i) raw[i] = ((const u16x8*)yp)[i];
#pragma unroll
      for (int i = 0; i < 32; ++i) v[i] = bf2f(raw[i >> 3][i & 7]);
    }
    float s = 0.f, s2 = 0.f;
#pragma unroll
    for (int i = 0; i < 32; ++i) { s += v[i]; s2 += v[i] * v[i]; }
    sm_red[0][part][n] = s;
    sm_red[1][part][n] = s2;
    __syncthreads();
    float tsum = sm_red[0][0][n] + sm_red[0][1][n] + sm_red[0][2][n];
    float tsq  = sm_red[1][0][n] + sm_red[1][1][n] + sm_red[1][2][n];
    float mean = tsum * (1.0f / 96.0f);
    float var = fmaxf(tsq * (1.0f / 96.0f) - mean * mean, 0.0f);
    float rstd = rsqrtf(var + 1e-5f);
#pragma unroll
    for (int i = 0; i < 32; ++i) {
      int c = part * 32 + i;
      sm_z[n * Z_STR + c] = f2bf((v[i] - mean) * rstd * ldS(g2, isf, c) + ldS(b2, isf, c));
    }
  }
  __syncthreads();

  const int wv = tid >> 6;
  const int lane = tid & 63;
  const int quad = lane >> 4;
  const int l16 = lane & 15;

  // ---- fc1 + exact GELU ----
  {
#pragma unroll
    for (int nt4 = 0; nt4 < 4; ++nt4) {
      const int jcol = (wv * 4 + nt4) * 16 + l16;
      bf16x8 bw[3];
#pragma unroll
      for (int kt = 0; kt < 3; ++kt)
        bw[kt] = ld8G(w_fc1, isf, (size_t)jcol * C_DIM + kt * 32 + quad * 8);
      const float bias = ldS(b_fc1, isf, jcol);
      for (int mt = 0; mt < 8; ++mt) {
        f32x4 acc = fzero4();
#pragma unroll
        for (int kt = 0; kt < 3; ++kt) {
          bf16x8 a = ld8(sm_z + (mt * 16 + l16) * Z_STR + kt * 32 + quad * 8);
          acc = mfma16(a, bw[kt], acc);
        }
#pragma unroll
        for (int r = 0; r < 4; ++r) {
          float hv = acc[r] + bias;
          float g = 0.5f * hv * (1.0f + erff(hv * 0.70710678118654752f));
          sm_h[(mt * 16 + quad * 4 + r) * H_STR + jcol] = f2bf(g);
        }
      }
    }
  }
  __syncthreads();

  // ---- fc2 + residual ----
  {
    const int jcol = wv * 16 + l16;
    bf16x8 bw[12];
#pragma unroll
    for (int kt = 0; kt < 12; ++kt)
      bw[kt] = ld8G(w_fc2, isf, (size_t)jcol * 384 + kt * 32 + quad * 8);
    const float bias = ldS(b_fc2, isf, jcol);
    for (int mt = 0; mt < 8; ++mt) {
      f32x4 acc = fzero4();
#pragma unroll
      for (int kt = 0; kt < 12; ++kt) {
        bf16x8 a = ld8(sm_h + (mt * 16 + l16) * H_STR + kt * 32 + quad * 8);
        acc = mfma16(a, bw[kt], acc);
      }
#pragma unroll
      for (int r = 0; r < 4; ++r) {
        int row = mt * 16 + quad * 4 + r;
        size_t addr = (tok0 + row) * C_DIM + jcol;
        stO(yout, isf, addr, ldS(yout, isf, addr) + acc[r] + bias);
      }
    }
  }
}

// =====================================================================
extern "C" void kernel_launch(void* const* d_in, const int* in_sizes, int n_in,
                              void* d_out, int out_size, void* d_ws, size_t ws_size,
                              hipStream_t stream) {
  const void* x      = d_in[0];
  // d_in[1] = attn_mask (recomputed analytically; unused)
  const void* g1     = d_in[2];
  const void* b1     = d_in[3];
  const void* w_qkv  = d_in[4];
  const void* b_qkv  = d_in[5];
  const void* w_proj = d_in[6];
  const void* b_proj = d_in[7];
  const void* g2     = d_in[8];
  const void* b2     = d_in[9];
  const void* w_fc1  = d_in[10];
  const void* b_fc1  = d_in[11];
  const void* w_fc2  = d_in[12];
  const void* b_fc2  = d_in[13];
  int* flag = (int*)d_ws;

  dtype_sniff<<<1, 64, 0, stream>>>((const unsigned short*)x, flag);
  swin_attn_kernel<<<2048, 384, 0, stream>>>(x, g1, b1, w_qkv, b_qkv, w_proj, b_proj, d_out, flag);
  swin_mlp_kernel<<<2048, 384, 0, stream>>>(g2, b2, w_fc1, b_fc1, w_fc2, b_fc2, d_out, flag);
}